// Round 2
// 384.334 us; speedup vs baseline: 1.1238x; 1.1238x over previous
//
#include <hip/hip_runtime.h>
#include <hip/hip_bf16.h>
#include <hip/hip_fp16.h>

#define HEADS 8
#define BB 32
#define CC 512
#define NN 1024   // tokens
#define DD 64     // head dim

typedef _Float16 f16;
typedef __attribute__((ext_vector_type(8))) _Float16 f16x8;
typedef __attribute__((ext_vector_type(4))) _Float16 f16x4;
typedef __attribute__((ext_vector_type(2))) __fp16 hf16x2;   // cvt_pkrtz native type
typedef __attribute__((ext_vector_type(4))) float f32x4;

// ---------------------------------------------------------------------------
// wconv: W fp32 [3C][C] -> Wh fp16 (one-time, ~1.5 MB)
// ---------------------------------------------------------------------------
__global__ __launch_bounds__(256) void wconv(
    const float* __restrict__ W, f16* __restrict__ Wh)
{
    const size_t i = ((size_t)blockIdx.x * 256 + threadIdx.x) * 8;
    float4 a = *(const float4*)(W + i);
    float4 b = *(const float4*)(W + i + 4);
    f16x8 h = {(f16)a.x, (f16)a.y, (f16)a.z, (f16)a.w,
               (f16)b.x, (f16)b.y, (f16)b.z, (f16)b.w};
    *(f16x8*)(Wh + i) = h;
}

// ---------------------------------------------------------------------------
// prep_x: xt[b][m][c] fp16  <-  x[b][c][m] fp32   (LDS 64x64 transpose)
// ---------------------------------------------------------------------------
__global__ __launch_bounds__(256) void prep_x(
    const float* __restrict__ x, f16* __restrict__ xt)
{
    __shared__ f16 T[64][65];
    const int tid = threadIdx.x;
    const int c0 = blockIdx.x * 64;
    const int m0 = blockIdx.y * 64;
    const int b  = blockIdx.z;
    const float* xb = x + (size_t)b * CC * NN;

    const int m_l = tid & 63, c_l = tid >> 6;
    #pragma unroll
    for (int s = 0; s < 16; ++s) {
        const int cr = s * 4 + c_l;
        T[cr][m_l] = (f16)xb[(size_t)(c0 + cr) * NN + m0 + m_l];
    }
    __syncthreads();
    const int m_r = tid >> 2, cq = (tid & 3) * 16;
    f16 buf[16];
    #pragma unroll
    for (int j = 0; j < 16; ++j) buf[j] = T[cq + j][m_r];
    f16* dst = xt + ((size_t)b * NN + m0 + m_r) * CC + c0 + cq;
    *(f16x8*)dst       = *(f16x8*)&buf[0];
    *(f16x8*)(dst + 8) = *(f16x8*)&buf[8];
}

// ---------------------------------------------------------------------------
// qkv_mfma: out[m][o] = sum_c xt[m][c] * Wh[o][c]   (fp16 MFMA, fp32 acc)
// Block tile 128m x 128o, BK=64; 4 waves, each 64m x 64o.  Pure f16x8 staging.
// Epilogue: Qh [b][p][n][d]; Kh = K + rp; Vt [b][p][d][n] (transposed).
// (unchanged from verified R7 baseline)
// ---------------------------------------------------------------------------
#define QST 72

__global__ __launch_bounds__(256) void qkv_mfma(
    const f16*  __restrict__ xt,     // [B*N][C]
    const f16*  __restrict__ Wh,     // [3C][C]
    const float* __restrict__ h_pos, // [L][C]
    const float* __restrict__ w_pos, // [L][C]
    f16* __restrict__ Qh, f16* __restrict__ Kh, f16* __restrict__ Vt)
{
    __shared__ f16 Xs[128 * QST];
    __shared__ f16 Ws[128 * QST];

    const int tid  = threadIdx.x;
    const int wave = tid >> 6, lane = tid & 63;
    const int ln = lane & 15, quad = lane >> 4;
    const int o0  = blockIdx.x * 128;
    const int mg0 = blockIdx.y * 128;
    const int mw = (wave & 1) * 64, ow = (wave >> 1) * 64;

    f32x4 acc[4][4];
    #pragma unroll
    for (int ia = 0; ia < 4; ++ia)
        #pragma unroll
        for (int ib = 0; ib < 4; ++ib) acc[ia][ib] = (f32x4){0.f, 0.f, 0.f, 0.f};

    const int srow = tid >> 1;
    const int ssub = (tid & 1) * 32;

    for (int ct = 0; ct < 8; ++ct) {
        const int c0 = ct * 64;
        __syncthreads();
        {
            const f16* xg = xt + (size_t)(mg0 + srow) * CC + c0 + ssub;
            const f16* wg = Wh + (size_t)(o0 + srow) * CC + c0 + ssub;
            #pragma unroll
            for (int i = 0; i < 4; ++i) {
                *(f16x8*)&Xs[srow * QST + ssub + i * 8] = *(const f16x8*)(xg + i * 8);
                *(f16x8*)&Ws[srow * QST + ssub + i * 8] = *(const f16x8*)(wg + i * 8);
            }
        }
        __syncthreads();
        #pragma unroll
        for (int ks = 0; ks < 2; ++ks) {
            f16x8 a[4], bf[4];
            #pragma unroll
            for (int f = 0; f < 4; ++f) {
                a[f]  = *(const f16x8*)&Xs[(mw + f * 16 + ln) * QST + ks * 32 + quad * 8];
                bf[f] = *(const f16x8*)&Ws[(ow + f * 16 + ln) * QST + ks * 32 + quad * 8];
            }
            #pragma unroll
            for (int ia = 0; ia < 4; ++ia)
                #pragma unroll
                for (int ib = 0; ib < 4; ++ib)
                    acc[ia][ib] = __builtin_amdgcn_mfma_f32_16x16x32_f16(
                        a[ia], bf[ib], acc[ia][ib], 0, 0, 0);
        }
    }

    const int region = o0 >> 9;             // 0=Q, 1=K, 2=V
    const int ob = o0 + ow;
    const int p  = (ob >> 6) & 7;
    const int b  = mg0 >> 10;
    const int n0 = (mg0 & 1023) + mw;

    if (region < 2) {
        f16* dst = (region == 0) ? Qh : Kh;
        const size_t hb = (size_t)(b * HEADS + p) * NN * DD;
        #pragma unroll
        for (int ib = 0; ib < 4; ++ib) {
            const int d = ib * 16 + ln;
            #pragma unroll
            for (int ia = 0; ia < 4; ++ia) {
                #pragma unroll
                for (int r = 0; r < 4; ++r) {
                    const int n = n0 + ia * 16 + quad * 4 + r;
                    float v = acc[ia][ib][r];
                    if (region == 1) {
                        const int c = p * DD + d;
                        v += h_pos[(n >> 5) * CC + c] + w_pos[(n & 31) * CC + c];
                    }
                    dst[hb + (size_t)n * DD + d] = (f16)v;
                }
            }
        }
    } else {
        const size_t vb = (size_t)(b * HEADS + p) * DD * NN;
        #pragma unroll
        for (int ib = 0; ib < 4; ++ib) {
            const int d = ib * 16 + ln;
            #pragma unroll
            for (int ia = 0; ia < 4; ++ia) {
                const int n = n0 + ia * 16 + quad * 4;
                f16x4 pk = {(f16)acc[ia][ib][0], (f16)acc[ia][ib][1],
                            (f16)acc[ia][ib][2], (f16)acc[ia][ib][3]};
                *(f16x4*)&Vt[vb + (size_t)d * NN + n] = pk;
            }
        }
    }
}

// ---------------------------------------------------------------------------
// attn_kernel R8: swapped-QK^T in-register softmax (m214 technique, 16x16).
//  * s[nt] = mfma(K_frag, Q_frag)  ->  S^T: lane holds 16 keys for q = ln.
//  * Row max: 15 in-reg fmax + 2 shfl_xor (was 16 shuffles); 1 alpha/lane.
//  * Row sum in fp32 regs (+2 shfl) -- removes the 2 `ones` MFMAs per kt.
//  * P packed via v_cvt_pkrtz -> 4 ds_write_b64 (was 16 conflicted b16).
//  * PS wave-private both sides -> B3 barrier replaced by s_waitcnt lgkmcnt(0).
//  * PV as O^T = mfma(V^T_frag, P_frag): alpha/l/output all keyed on q=ln.
//  * T14: next K/V tile global->reg loads issued right after the LDS write.
// ---------------------------------------------------------------------------
#define KST 72

__global__ __launch_bounds__(256) void attn_kernel(
    const f16* __restrict__ Qh, const f16* __restrict__ Kh,
    const f16* __restrict__ Vt, float* __restrict__ out)
{
    __shared__ f16 KS [64 * KST];
    __shared__ f16 VtS[64 * KST];
    __shared__ f16 PS [4][16 * KST];

    const int tid  = threadIdx.x;
    const int wave = tid >> 6;
    const int lane = tid & 63;
    const int ln   = lane & 15;
    const int quad = lane >> 4;

    const int qt = blockIdx.x;
    const int p  = blockIdx.y;
    const int b  = blockIdx.z;
    const size_t hb = (size_t)(b * HEADS + p) * NN * DD;

    // Q fragment: lane holds Q[q = qrow][k = ks*32 + quad*8 + j]  (B-frag, n=ln)
    const int qrow = qt * 64 + wave * 16 + ln;
    f16x8 qf[2];
    #pragma unroll
    for (int ks = 0; ks < 2; ++ks)
        qf[ks] = *(const f16x8*)(Qh + hb + (size_t)qrow * DD + ks * 32 + quad * 8);

    // o[dt][r] = O[q = ln][d = dt*16 + quad*4 + r]
    f32x4 o[4];
    #pragma unroll
    for (int dt = 0; dt < 4; ++dt) o[dt] = (f32x4){0.f, 0.f, 0.f, 0.f};
    float lrun = 0.f;
    float mrun = -__builtin_inff();

    const int sr = tid >> 2, sc = (tid & 3) * 16;

    // Prologue: tile 0 into staging registers.
    f16x8 kreg0, kreg1, vreg0, vreg1;
    {
        const size_t gk = hb + (size_t)sr * DD + sc;
        kreg0 = *(const f16x8*)(Kh + gk);
        kreg1 = *(const f16x8*)(Kh + gk + 8);
        const size_t gv = hb + (size_t)sr * NN + sc;
        vreg0 = *(const f16x8*)(Vt + gv);
        vreg1 = *(const f16x8*)(Vt + gv + 8);
    }

    f16* Pw = &PS[wave][0];

    for (int kt = 0; kt < 16; ++kt) {
        __syncthreads();   // B1: all waves done reading previous tile's LDS
        *(f16x8*)&KS [sr * KST + sc]     = kreg0;
        *(f16x8*)&KS [sr * KST + sc + 8] = kreg1;
        *(f16x8*)&VtS[sr * KST + sc]     = vreg0;
        *(f16x8*)&VtS[sr * KST + sc + 8] = vreg1;
        if (kt < 15) {   // T14: next-tile loads fly during this tile's compute
            const size_t gk = hb + (size_t)((kt + 1) * 64 + sr) * DD + sc;
            kreg0 = *(const f16x8*)(Kh + gk);
            kreg1 = *(const f16x8*)(Kh + gk + 8);
            const size_t gv = hb + (size_t)sr * NN + (kt + 1) * 64 + sc;
            vreg0 = *(const f16x8*)(Vt + gv);
            vreg1 = *(const f16x8*)(Vt + gv + 8);
        }
        __syncthreads();   // B2: tile kt visible in LDS

        // S^T tile: s[nt][r] = S[q = ln][key = nt*16 + quad*4 + r]
        f32x4 s[4];
        #pragma unroll
        for (int nt = 0; nt < 4; ++nt) s[nt] = (f32x4){0.f, 0.f, 0.f, 0.f};
        #pragma unroll
        for (int ks = 0; ks < 2; ++ks) {
            #pragma unroll
            for (int nt = 0; nt < 4; ++nt) {
                f16x8 bk = *(const f16x8*)&KS[(nt * 16 + ln) * KST + ks * 32 + quad * 8];
                s[nt] = __builtin_amdgcn_mfma_f32_16x16x32_f16(bk, qf[ks], s[nt], 0, 0, 0);
            }
        }

        // Row max for q=ln: 15 in-reg fmax + 2 cross-quad shuffles.
        float mx = s[0][0];
        #pragma unroll
        for (int nt = 0; nt < 4; ++nt)
            #pragma unroll
            for (int r = 0; r < 4; ++r) mx = fmaxf(mx, s[nt][r]);
        mx = fmaxf(mx, __shfl_xor(mx, 16));
        mx = fmaxf(mx, __shfl_xor(mx, 32));
        const float mnew = fmaxf(mrun, mx);
        const float alpha = __expf(mrun - mnew);   // 0 on first tile
        mrun = mnew;

        // P = exp(S-m): fp32 row-sum in regs, packed f16 pairs to wave-private LDS.
        float lsum = 0.f;
        #pragma unroll
        for (int nt = 0; nt < 4; ++nt) {
            const float p0 = __expf(s[nt][0] - mrun);
            const float p1 = __expf(s[nt][1] - mrun);
            const float p2 = __expf(s[nt][2] - mrun);
            const float p3 = __expf(s[nt][3] - mrun);
            lsum += (p0 + p1) + (p2 + p3);
            hf16x2 lo = __builtin_amdgcn_cvt_pkrtz(p0, p1);
            hf16x2 hi = __builtin_amdgcn_cvt_pkrtz(p2, p3);
            f16x4 pk = {(f16)lo.x, (f16)lo.y, (f16)hi.x, (f16)hi.y};
            *(f16x4*)&Pw[ln * KST + nt * 16 + quad * 4] = pk;   // ds_write_b64
        }
        lsum += __shfl_xor(lsum, 16);
        lsum += __shfl_xor(lsum, 32);
        lrun = lrun * alpha + lsum;

        // Register-only rescale while the P-stores drain.
        #pragma unroll
        for (int dt = 0; dt < 4; ++dt) {
            o[dt][0] *= alpha; o[dt][1] *= alpha;
            o[dt][2] *= alpha; o[dt][3] *= alpha;
        }

        // PS is wave-private: wave-local LDS drain instead of __syncthreads.
        asm volatile("s_waitcnt lgkmcnt(0)" ::: "memory");

        // O^T += V^T P :  o[dt] = mfma(A=V^T frag, B=P frag, o[dt])
        #pragma unroll
        for (int ks = 0; ks < 2; ++ks) {
            f16x8 pa = *(const f16x8*)&Pw[ln * KST + ks * 32 + quad * 8];
            #pragma unroll
            for (int dt = 0; dt < 4; ++dt) {
                f16x8 vb = *(const f16x8*)&VtS[(dt * 16 + ln) * KST + ks * 32 + quad * 8];
                o[dt] = __builtin_amdgcn_mfma_f32_16x16x32_f16(vb, pa, o[dt], 0, 0, 0);
            }
        }
    }

    // Epilogue: lane holds O[q=ln][d = dt*16+quad*4+r], l for q=ln.
    // out[b][c = p*64 + d][n = qrow]; 16 lanes of ln give 64B segments.
    const float inv = 1.0f / lrun;
    const int nq = qt * 64 + wave * 16 + ln;
    #pragma unroll
    for (int dt = 0; dt < 4; ++dt) {
        const int c = p * DD + dt * 16 + quad * 4;
        #pragma unroll
        for (int r = 0; r < 4; ++r)
            out[((size_t)b * CC + c + r) * NN + nq] = o[dt][r] * inv;
    }
}

extern "C" void kernel_launch(void* const* d_in, const int* in_sizes, int n_in,
                              void* d_out, int out_size, void* d_ws, size_t ws_size,
                              hipStream_t stream) {
    const float* x     = (const float*)d_in[0];
    const float* qkv_w = (const float*)d_in[1];
    const float* h_pos = (const float*)d_in[2];
    const float* w_pos = (const float*)d_in[3];
    float* out = (float*)d_out;

    const size_t PT = (size_t)BB * HEADS * NN * DD;  // 16,777,216 elems
    f16* xt = (f16*)d_ws;
    f16* Qh = xt + PT;
    f16* Kh = Qh + PT;
    f16* Vt = Kh + PT;
    f16* Wh = Vt + PT;   // 3C*C = 786,432 f16; total ~135.7 MB (fits)

    wconv<<<dim3(3 * CC * CC / (256 * 8)), 256, 0, stream>>>(qkv_w, Wh);
    prep_x<<<dim3(CC / 64, NN / 64, BB), 256, 0, stream>>>(x, xt);
    qkv_mfma<<<dim3(12, 256), 256, 0, stream>>>(xt, Wh, h_pos, w_pos, Qh, Kh, Vt);
    attn_kernel<<<dim3(16, HEADS, BB), 256, 0, stream>>>(Qh, Kh, Vt, out);
}

// Round 3
// 381.188 us; speedup vs baseline: 1.1331x; 1.0083x over previous
//
#include <hip/hip_runtime.h>
#include <hip/hip_bf16.h>
#include <hip/hip_fp16.h>

#define HEADS 8
#define BB 32
#define CC 512
#define NN 1024   // tokens
#define DD 64     // head dim

typedef _Float16 f16;
typedef __attribute__((ext_vector_type(8))) _Float16 f16x8;
typedef __attribute__((ext_vector_type(4))) _Float16 f16x4;
typedef __attribute__((ext_vector_type(2))) __fp16 hf16x2;   // cvt_pkrtz native type
typedef __attribute__((ext_vector_type(4))) float f32x4;

// async global->LDS, 16B per lane; LDS dest is wave-uniform base + lane*16,
// global src is per-lane (m97/m173 pattern).
__device__ __forceinline__ void gload16(const f16* g, f16* l) {
    __builtin_amdgcn_global_load_lds(
        (const __attribute__((address_space(1))) void*)g,
        (__attribute__((address_space(3))) void*)l, 16, 0, 0);
}

// ---------------------------------------------------------------------------
// wconv: W fp32 [3C][C] -> Wh fp16 (one-time, ~1.5 MB)
// ---------------------------------------------------------------------------
__global__ __launch_bounds__(256) void wconv(
    const float* __restrict__ W, f16* __restrict__ Wh)
{
    const size_t i = ((size_t)blockIdx.x * 256 + threadIdx.x) * 8;
    float4 a = *(const float4*)(W + i);
    float4 b = *(const float4*)(W + i + 4);
    f16x8 h = {(f16)a.x, (f16)a.y, (f16)a.z, (f16)a.w,
               (f16)b.x, (f16)b.y, (f16)b.z, (f16)b.w};
    *(f16x8*)(Wh + i) = h;
}

// ---------------------------------------------------------------------------
// prep_x: xt[b][m][c] fp16  <-  x[b][c][m] fp32   (LDS 64x64 transpose)
// ---------------------------------------------------------------------------
__global__ __launch_bounds__(256) void prep_x(
    const float* __restrict__ x, f16* __restrict__ xt)
{
    __shared__ f16 T[64][65];
    const int tid = threadIdx.x;
    const int c0 = blockIdx.x * 64;
    const int m0 = blockIdx.y * 64;
    const int b  = blockIdx.z;
    const float* xb = x + (size_t)b * CC * NN;

    const int m_l = tid & 63, c_l = tid >> 6;
    #pragma unroll
    for (int s = 0; s < 16; ++s) {
        const int cr = s * 4 + c_l;
        T[cr][m_l] = (f16)xb[(size_t)(c0 + cr) * NN + m0 + m_l];
    }
    __syncthreads();
    const int m_r = tid >> 2, cq = (tid & 3) * 16;
    f16 buf[16];
    #pragma unroll
    for (int j = 0; j < 16; ++j) buf[j] = T[cq + j][m_r];
    f16* dst = xt + ((size_t)b * NN + m0 + m_r) * CC + c0 + cq;
    *(f16x8*)dst       = *(f16x8*)&buf[0];
    *(f16x8*)(dst + 8) = *(f16x8*)&buf[8];
}

// ---------------------------------------------------------------------------
// qkv_mfma R9: m97-style staging.  Linear LDS [128][64] (no pad), 8x
// global_load_lds_dwordx4 per wave per K-step (wave w stages rows
// [w*32, w*32+32) of both tiles).  2 barriers per K-step; fragment reads and
// MFMA/epilogue bitwise-identical to R8 (stride 72 -> 64 only).
// XCD-grouped 1D grid: 12 o-tiles sharing an A-panel land on one XCD.
// ---------------------------------------------------------------------------
__global__ __launch_bounds__(256) void qkv_mfma(
    const f16*  __restrict__ xt,     // [B*N][C]
    const f16*  __restrict__ Wh,     // [3C][C]
    const float* __restrict__ h_pos, // [L][C]
    const float* __restrict__ w_pos, // [L][C]
    f16* __restrict__ Qh, f16* __restrict__ Kh, f16* __restrict__ Vt)
{
    __shared__ f16 Xs[128 * 64];
    __shared__ f16 Ws[128 * 64];

    const int tid  = threadIdx.x;
    const int wave = tid >> 6, lane = tid & 63;
    const int ln = lane & 15, quad = lane >> 4;

    // XCD swizzle: grid 3072 = 8 XCDs x 32 m-tiles x 12 o-tiles.
    const unsigned bid  = blockIdx.x;
    const unsigned xcd  = bid & 7;
    const unsigned slot = bid >> 3;            // 0..383
    const unsigned ot   = slot % 12u;
    const unsigned mt   = xcd * 32u + slot / 12u;
    const int o0  = (int)ot * 128;
    const int mg0 = (int)mt * 128;
    const int mw = (wave & 1) * 64, ow = (wave >> 1) * 64;

    f32x4 acc[4][4];
    #pragma unroll
    for (int ia = 0; ia < 4; ++ia)
        #pragma unroll
        for (int ib = 0; ib < 4; ++ib) acc[ia][ib] = (f32x4){0.f, 0.f, 0.f, 0.f};

    // Staging geometry: lane l covers row (l>>3), 16B chunk (l&7) of each
    // 8-row stripe; wave w owns rows [w*32, w*32+32).
    const int sr = wave * 32 + (lane >> 3);
    const int sc = (lane & 7) * 8;
    const f16* xg = xt + (size_t)(mg0 + sr) * CC + sc;
    const f16* wg = Wh + (size_t)(o0  + sr) * CC + sc;
    f16* xl = &Xs[(wave * 32) * 64];
    f16* wl = &Ws[(wave * 32) * 64];

    for (int ct = 0; ct < 8; ++ct) {
        const int c0 = ct * 64;
        __syncthreads();
        #pragma unroll
        for (int i = 0; i < 4; ++i) {
            gload16(xg + (size_t)i * 8 * CC + c0, xl + i * 8 * 64);
            gload16(wg + (size_t)i * 8 * CC + c0, wl + i * 8 * 64);
        }
        __syncthreads();   // drains vmcnt(0): tile visible
        #pragma unroll
        for (int ks = 0; ks < 2; ++ks) {
            f16x8 a[4], bf[4];
            #pragma unroll
            for (int f = 0; f < 4; ++f) {
                a[f]  = *(const f16x8*)&Xs[(mw + f * 16 + ln) * 64 + ks * 32 + quad * 8];
                bf[f] = *(const f16x8*)&Ws[(ow + f * 16 + ln) * 64 + ks * 32 + quad * 8];
            }
            #pragma unroll
            for (int ia = 0; ia < 4; ++ia)
                #pragma unroll
                for (int ib = 0; ib < 4; ++ib)
                    acc[ia][ib] = __builtin_amdgcn_mfma_f32_16x16x32_f16(
                        a[ia], bf[ib], acc[ia][ib], 0, 0, 0);
        }
    }

    const int region = o0 >> 9;             // 0=Q, 1=K, 2=V
    const int ob = o0 + ow;
    const int p  = (ob >> 6) & 7;
    const int b  = mg0 >> 10;
    const int n0 = (mg0 & 1023) + mw;

    if (region < 2) {
        f16* dst = (region == 0) ? Qh : Kh;
        const size_t hb = (size_t)(b * HEADS + p) * NN * DD;
        #pragma unroll
        for (int ib = 0; ib < 4; ++ib) {
            const int d = ib * 16 + ln;
            #pragma unroll
            for (int ia = 0; ia < 4; ++ia) {
                #pragma unroll
                for (int r = 0; r < 4; ++r) {
                    const int n = n0 + ia * 16 + quad * 4 + r;
                    float v = acc[ia][ib][r];
                    if (region == 1) {
                        const int c = p * DD + d;
                        v += h_pos[(n >> 5) * CC + c] + w_pos[(n & 31) * CC + c];
                    }
                    dst[hb + (size_t)n * DD + d] = (f16)v;
                }
            }
        }
    } else {
        const size_t vb = (size_t)(b * HEADS + p) * DD * NN;
        #pragma unroll
        for (int ib = 0; ib < 4; ++ib) {
            const int d = ib * 16 + ln;
            #pragma unroll
            for (int ia = 0; ia < 4; ++ia) {
                const int n = n0 + ia * 16 + quad * 4;
                f16x4 pk = {(f16)acc[ia][ib][0], (f16)acc[ia][ib][1],
                            (f16)acc[ia][ib][2], (f16)acc[ia][ib][3]};
                *(f16x4*)&Vt[vb + (size_t)d * NN + n] = pk;
            }
        }
    }
}

// ---------------------------------------------------------------------------
// attn_kernel R9 = R8 (swapped-QK^T in-register softmax, verified) +
// XCD-grouped 1D grid: the 16 qt-blocks sharing one (b,p)'s K/V (256 KB)
// all land on the same XCD -> K/V fetched once per XCD, not 8x.
// ---------------------------------------------------------------------------
#define KST 72

__global__ __launch_bounds__(256) void attn_kernel(
    const f16* __restrict__ Qh, const f16* __restrict__ Kh,
    const f16* __restrict__ Vt, float* __restrict__ out)
{
    __shared__ f16 KS [64 * KST];
    __shared__ f16 VtS[64 * KST];
    __shared__ f16 PS [4][16 * KST];

    const int tid  = threadIdx.x;
    const int wave = tid >> 6;
    const int lane = tid & 63;
    const int ln   = lane & 15;
    const int quad = lane >> 4;

    // XCD swizzle: grid 4096 = 8 XCDs x 32 (b,p)-groups x 16 qt.
    const unsigned bid  = blockIdx.x;
    const unsigned xcd  = bid & 7;
    const unsigned slot = bid >> 3;            // 0..511
    const int qt = (int)(slot & 15u);
    const unsigned g = xcd * 32u + (slot >> 4);  // 0..255
    const int b = (int)(g >> 3);
    const int p = (int)(g & 7u);
    const size_t hb = (size_t)(b * HEADS + p) * NN * DD;

    // Q fragment: lane holds Q[q = qrow][k = ks*32 + quad*8 + j]  (B-frag, n=ln)
    const int qrow = qt * 64 + wave * 16 + ln;
    f16x8 qf[2];
    #pragma unroll
    for (int ks = 0; ks < 2; ++ks)
        qf[ks] = *(const f16x8*)(Qh + hb + (size_t)qrow * DD + ks * 32 + quad * 8);

    // o[dt][r] = O[q = ln][d = dt*16 + quad*4 + r]
    f32x4 o[4];
    #pragma unroll
    for (int dt = 0; dt < 4; ++dt) o[dt] = (f32x4){0.f, 0.f, 0.f, 0.f};
    float lrun = 0.f;
    float mrun = -__builtin_inff();

    const int sr = tid >> 2, sc = (tid & 3) * 16;

    // Prologue: tile 0 into staging registers.
    f16x8 kreg0, kreg1, vreg0, vreg1;
    {
        const size_t gk = hb + (size_t)sr * DD + sc;
        kreg0 = *(const f16x8*)(Kh + gk);
        kreg1 = *(const f16x8*)(Kh + gk + 8);
        const size_t gv = hb + (size_t)sr * NN + sc;
        vreg0 = *(const f16x8*)(Vt + gv);
        vreg1 = *(const f16x8*)(Vt + gv + 8);
    }

    f16* Pw = &PS[wave][0];

    for (int kt = 0; kt < 16; ++kt) {
        __syncthreads();   // B1: all waves done reading previous tile's LDS
        *(f16x8*)&KS [sr * KST + sc]     = kreg0;
        *(f16x8*)&KS [sr * KST + sc + 8] = kreg1;
        *(f16x8*)&VtS[sr * KST + sc]     = vreg0;
        *(f16x8*)&VtS[sr * KST + sc + 8] = vreg1;
        if (kt < 15) {   // T14: next-tile loads fly during this tile's compute
            const size_t gk = hb + (size_t)((kt + 1) * 64 + sr) * DD + sc;
            kreg0 = *(const f16x8*)(Kh + gk);
            kreg1 = *(const f16x8*)(Kh + gk + 8);
            const size_t gv = hb + (size_t)sr * NN + (kt + 1) * 64 + sc;
            vreg0 = *(const f16x8*)(Vt + gv);
            vreg1 = *(const f16x8*)(Vt + gv + 8);
        }
        __syncthreads();   // B2: tile kt visible in LDS

        // S^T tile: s[nt][r] = S[q = ln][key = nt*16 + quad*4 + r]
        f32x4 s[4];
        #pragma unroll
        for (int nt = 0; nt < 4; ++nt) s[nt] = (f32x4){0.f, 0.f, 0.f, 0.f};
        #pragma unroll
        for (int ks = 0; ks < 2; ++ks) {
            #pragma unroll
            for (int nt = 0; nt < 4; ++nt) {
                f16x8 bk = *(const f16x8*)&KS[(nt * 16 + ln) * KST + ks * 32 + quad * 8];
                s[nt] = __builtin_amdgcn_mfma_f32_16x16x32_f16(bk, qf[ks], s[nt], 0, 0, 0);
            }
        }

        // Row max for q=ln: 15 in-reg fmax + 2 cross-quad shuffles.
        float mx = s[0][0];
        #pragma unroll
        for (int nt = 0; nt < 4; ++nt)
            #pragma unroll
            for (int r = 0; r < 4; ++r) mx = fmaxf(mx, s[nt][r]);
        mx = fmaxf(mx, __shfl_xor(mx, 16));
        mx = fmaxf(mx, __shfl_xor(mx, 32));
        const float mnew = fmaxf(mrun, mx);
        const float alpha = __expf(mrun - mnew);   // 0 on first tile
        mrun = mnew;

        // P = exp(S-m): fp32 row-sum in regs, packed f16 pairs to wave-private LDS.
        float lsum = 0.f;
        #pragma unroll
        for (int nt = 0; nt < 4; ++nt) {
            const float p0 = __expf(s[nt][0] - mrun);
            const float p1 = __expf(s[nt][1] - mrun);
            const float p2 = __expf(s[nt][2] - mrun);
            const float p3 = __expf(s[nt][3] - mrun);
            lsum += (p0 + p1) + (p2 + p3);
            hf16x2 lo = __builtin_amdgcn_cvt_pkrtz(p0, p1);
            hf16x2 hi = __builtin_amdgcn_cvt_pkrtz(p2, p3);
            f16x4 pk = {(f16)lo.x, (f16)lo.y, (f16)hi.x, (f16)hi.y};
            *(f16x4*)&Pw[ln * KST + nt * 16 + quad * 4] = pk;   // ds_write_b64
        }
        lsum += __shfl_xor(lsum, 16);
        lsum += __shfl_xor(lsum, 32);
        lrun = lrun * alpha + lsum;

        // Register-only rescale while the P-stores drain.
        #pragma unroll
        for (int dt = 0; dt < 4; ++dt) {
            o[dt][0] *= alpha; o[dt][1] *= alpha;
            o[dt][2] *= alpha; o[dt][3] *= alpha;
        }

        // PS is wave-private: wave-local LDS drain instead of __syncthreads.
        asm volatile("s_waitcnt lgkmcnt(0)" ::: "memory");

        // O^T += V^T P :  o[dt] = mfma(A=V^T frag, B=P frag, o[dt])
        #pragma unroll
        for (int ks = 0; ks < 2; ++ks) {
            f16x8 pa = *(const f16x8*)&Pw[ln * KST + ks * 32 + quad * 8];
            #pragma unroll
            for (int dt = 0; dt < 4; ++dt) {
                f16x8 vb = *(const f16x8*)&VtS[(dt * 16 + ln) * KST + ks * 32 + quad * 8];
                o[dt] = __builtin_amdgcn_mfma_f32_16x16x32_f16(vb, pa, o[dt], 0, 0, 0);
            }
        }
    }

    // Epilogue: lane holds O[q=ln][d = dt*16+quad*4+r], l for q=ln.
    const float inv = 1.0f / lrun;
    const int nq = qt * 64 + wave * 16 + ln;
    #pragma unroll
    for (int dt = 0; dt < 4; ++dt) {
        const int c = p * DD + dt * 16 + quad * 4;
        #pragma unroll
        for (int r = 0; r < 4; ++r)
            out[((size_t)b * CC + c + r) * NN + nq] = o[dt][r] * inv;
    }
}

extern "C" void kernel_launch(void* const* d_in, const int* in_sizes, int n_in,
                              void* d_out, int out_size, void* d_ws, size_t ws_size,
                              hipStream_t stream) {
    const float* x     = (const float*)d_in[0];
    const float* qkv_w = (const float*)d_in[1];
    const float* h_pos = (const float*)d_in[2];
    const float* w_pos = (const float*)d_in[3];
    float* out = (float*)d_out;

    const size_t PT = (size_t)BB * HEADS * NN * DD;  // 16,777,216 elems
    f16* xt = (f16*)d_ws;
    f16* Qh = xt + PT;
    f16* Kh = Qh + PT;
    f16* Vt = Kh + PT;
    f16* Wh = Vt + PT;   // 3C*C = 786,432 f16; total ~135.7 MB (fits)

    wconv<<<dim3(3 * CC * CC / (256 * 8)), 256, 0, stream>>>(qkv_w, Wh);
    prep_x<<<dim3(CC / 64, NN / 64, BB), 256, 0, stream>>>(x, xt);
    qkv_mfma<<<dim3(3072), 256, 0, stream>>>(xt, Wh, h_pos, w_pos, Qh, Kh, Vt);
    attn_kernel<<<dim3(4096), 256, 0, stream>>>(Qh, Kh, Vt, out);
}

// Round 4
// 368.727 us; speedup vs baseline: 1.1713x; 1.0338x over previous
//
#include <hip/hip_runtime.h>
#include <hip/hip_bf16.h>
#include <hip/hip_fp16.h>

#define HEADS 8
#define BB 32
#define CC 512
#define NN 1024   // tokens
#define DD 64     // head dim

typedef _Float16 f16;
typedef __attribute__((ext_vector_type(8))) _Float16 f16x8;
typedef __attribute__((ext_vector_type(4))) _Float16 f16x4;
typedef __attribute__((ext_vector_type(2))) __fp16 hf16x2;   // cvt_pkrtz native type
typedef __attribute__((ext_vector_type(4))) float f32x4;

// async global->LDS, 16B per lane; LDS dest is wave-uniform base + lane*16,
// global src is per-lane (m97/m173 pattern).
__device__ __forceinline__ void gload16(const f16* g, f16* l) {
    __builtin_amdgcn_global_load_lds(
        (const __attribute__((address_space(1))) void*)g,
        (__attribute__((address_space(3))) void*)l, 16, 0, 0);
}

// wave-local LDS drain + compiler fence (verified pattern from attn R8).
__device__ __forceinline__ void wavefence() {
    asm volatile("s_waitcnt lgkmcnt(0)" ::: "memory");
}

// ---------------------------------------------------------------------------
// wconv: W fp32 [3C][C] -> Wh fp16 (one-time, ~1.5 MB)
// ---------------------------------------------------------------------------
__global__ __launch_bounds__(256) void wconv(
    const float* __restrict__ W, f16* __restrict__ Wh)
{
    const size_t i = ((size_t)blockIdx.x * 256 + threadIdx.x) * 8;
    float4 a = *(const float4*)(W + i);
    float4 b = *(const float4*)(W + i + 4);
    f16x8 h = {(f16)a.x, (f16)a.y, (f16)a.z, (f16)a.w,
               (f16)b.x, (f16)b.y, (f16)b.z, (f16)b.w};
    *(f16x8*)(Wh + i) = h;
}

// ---------------------------------------------------------------------------
// prep_x: xt[b][m][c] fp16  <-  x[b][c][m] fp32   (LDS 64x64 transpose)
// ---------------------------------------------------------------------------
__global__ __launch_bounds__(256) void prep_x(
    const float* __restrict__ x, f16* __restrict__ xt)
{
    __shared__ f16 T[64][65];
    const int tid = threadIdx.x;
    const int c0 = blockIdx.x * 64;
    const int m0 = blockIdx.y * 64;
    const int b  = blockIdx.z;
    const float* xb = x + (size_t)b * CC * NN;

    const int m_l = tid & 63, c_l = tid >> 6;
    #pragma unroll
    for (int s = 0; s < 16; ++s) {
        const int cr = s * 4 + c_l;
        T[cr][m_l] = (f16)xb[(size_t)(c0 + cr) * NN + m0 + m_l];
    }
    __syncthreads();
    const int m_r = tid >> 2, cq = (tid & 3) * 16;
    f16 buf[16];
    #pragma unroll
    for (int j = 0; j < 16; ++j) buf[j] = T[cq + j][m_r];
    f16* dst = xt + ((size_t)b * NN + m0 + m_r) * CC + c0 + cq;
    *(f16x8*)dst       = *(f16x8*)&buf[0];
    *(f16x8*)(dst + 8) = *(f16x8*)&buf[8];
}

// ---------------------------------------------------------------------------
// qkv_mfma R10: m97-style gload_lds staging (R9) + LDS-transposed epilogue.
// R9 post-mortem: epilogue was the bottleneck (64 scalar 2B stores/thread for
// Q/K, 16x8B scattered for V).  Now: acc -> per-wave LDS scratch (reusing the
// staging buffers after a barrier) -> f16x8 fully-coalesced global stores
// (8 wide stores/thread/pass instead of 64 scalars).
// Q is pre-scaled by log2(e) in fp32 (attn runs softmax in exp2 domain).
// ---------------------------------------------------------------------------
__global__ __launch_bounds__(256) void qkv_mfma(
    const f16*  __restrict__ xt,     // [B*N][C]
    const f16*  __restrict__ Wh,     // [3C][C]
    const float* __restrict__ h_pos, // [L][C]
    const float* __restrict__ w_pos, // [L][C]
    f16* __restrict__ Qh, f16* __restrict__ Kh, f16* __restrict__ Vt)
{
    __shared__ f16 SM[2 * 128 * 64];   // Xs | Ws, reused as epilogue scratch
    f16* Xs = SM;
    f16* Ws = SM + 128 * 64;

    const int tid  = threadIdx.x;
    const int wave = tid >> 6, lane = tid & 63;
    const int ln = lane & 15, quad = lane >> 4;

    // XCD swizzle: grid 3072 = 8 XCDs x 32 m-tiles x 12 o-tiles.
    const unsigned bid  = blockIdx.x;
    const unsigned xcd  = bid & 7;
    const unsigned slot = bid >> 3;            // 0..383
    const unsigned ot   = slot % 12u;
    const unsigned mt   = xcd * 32u + slot / 12u;
    const int o0  = (int)ot * 128;
    const int mg0 = (int)mt * 128;
    const int mw = (wave & 1) * 64, ow = (wave >> 1) * 64;

    f32x4 acc[4][4];
    #pragma unroll
    for (int ia = 0; ia < 4; ++ia)
        #pragma unroll
        for (int ib = 0; ib < 4; ++ib) acc[ia][ib] = (f32x4){0.f, 0.f, 0.f, 0.f};

    // Staging geometry: lane l covers row (l>>3), 16B chunk (l&7) of each
    // 8-row stripe; wave w owns rows [w*32, w*32+32).
    const int sr = wave * 32 + (lane >> 3);
    const int sc = (lane & 7) * 8;
    const f16* xg = xt + (size_t)(mg0 + sr) * CC + sc;
    const f16* wg = Wh + (size_t)(o0  + sr) * CC + sc;
    f16* xl = &Xs[(wave * 32) * 64];
    f16* wl = &Ws[(wave * 32) * 64];

    for (int ct = 0; ct < 8; ++ct) {
        const int c0 = ct * 64;
        __syncthreads();
        #pragma unroll
        for (int i = 0; i < 4; ++i) {
            gload16(xg + (size_t)i * 8 * CC + c0, xl + i * 8 * 64);
            gload16(wg + (size_t)i * 8 * CC + c0, wl + i * 8 * 64);
        }
        __syncthreads();   // drains vmcnt(0): tile visible
        #pragma unroll
        for (int ks = 0; ks < 2; ++ks) {
            f16x8 a[4], bf[4];
            #pragma unroll
            for (int f = 0; f < 4; ++f) {
                a[f]  = *(const f16x8*)&Xs[(mw + f * 16 + ln) * 64 + ks * 32 + quad * 8];
                bf[f] = *(const f16x8*)&Ws[(ow + f * 16 + ln) * 64 + ks * 32 + quad * 8];
            }
            #pragma unroll
            for (int ia = 0; ia < 4; ++ia)
                #pragma unroll
                for (int ib = 0; ib < 4; ++ib)
                    acc[ia][ib] = __builtin_amdgcn_mfma_f32_16x16x32_f16(
                        a[ia], bf[ib], acc[ia][ib], 0, 0, 0);
        }
    }

    __syncthreads();   // all waves done with Xs/Ws; safe to reuse as scratch
    f16* Ep = SM + wave * 4096;   // 8 KB per wave

    const int region = o0 >> 9;             // 0=Q, 1=K, 2=V
    const int ob = o0 + ow;
    const int p  = (ob >> 6) & 7;
    const int b  = mg0 >> 10;
    const int n0 = (mg0 & 1023) + mw;

    if (region < 2) {
        // Output layout [n][d]; LDS pass tile [64 n][34-stride d-half].
        f16* dst = (region == 0) ? Qh : Kh;
        const size_t hb = (size_t)(b * HEADS + p) * NN * DD;
        #pragma unroll
        for (int ph = 0; ph < 2; ++ph) {
            #pragma unroll
            for (int ibl = 0; ibl < 2; ++ibl) {
                const int ib = ph * 2 + ibl;
                const int d  = ib * 16 + ln;
                const int dl = ibl * 16 + ln;
                #pragma unroll
                for (int ia = 0; ia < 4; ++ia) {
                    #pragma unroll
                    for (int r = 0; r < 4; ++r) {
                        const int nl = ia * 16 + quad * 4 + r;
                        float v = acc[ia][ib][r];
                        if (region == 0) {
                            v *= 1.44269504f;   // log2(e): attn softmax in exp2 domain
                        } else {
                            const int n = n0 + nl;
                            const int c = p * DD + d;
                            v += h_pos[(n >> 5) * CC + c] + w_pos[(n & 31) * CC + c];
                        }
                        Ep[nl * 34 + dl] = (f16)v;
                    }
                }
            }
            wavefence();
            #pragma unroll
            for (int j = 0; j < 4; ++j) {
                const int nl = (lane >> 2) + 16 * j;
                const int dc = (lane & 3) * 8;
                f16x8 row = *(const f16x8*)&Ep[nl * 34 + dc];
                *(f16x8*)(dst + hb + (size_t)(n0 + nl) * DD + ph * 32 + dc) = row;
            }
            wavefence();
        }
    } else {
        // Output layout [d][n]; LDS pass tile [32 d][68-stride n].
        const size_t vb = (size_t)(b * HEADS + p) * DD * NN;
        #pragma unroll
        for (int ph = 0; ph < 2; ++ph) {
            #pragma unroll
            for (int ibl = 0; ibl < 2; ++ibl) {
                const int ib = ph * 2 + ibl;
                const int dl = ibl * 16 + ln;
                #pragma unroll
                for (int ia = 0; ia < 4; ++ia) {
                    const int nl = ia * 16 + quad * 4;
                    f16x4 pk = {(f16)acc[ia][ib][0], (f16)acc[ia][ib][1],
                                (f16)acc[ia][ib][2], (f16)acc[ia][ib][3]};
                    *(f16x4*)&Ep[dl * 68 + nl] = pk;
                }
            }
            wavefence();
            #pragma unroll
            for (int j = 0; j < 4; ++j) {
                const int dl = (lane >> 3) + 8 * j;
                const int nc = (lane & 7) * 8;
                f16x8 row = *(const f16x8*)&Ep[dl * 68 + nc];
                *(f16x8*)(Vt + vb + (size_t)(ph * 32 + dl) * NN + n0 + nc) = row;
            }
            wavefence();
        }
    }
}

// ---------------------------------------------------------------------------
// attn_kernel R10 = R9 (swapped-QK^T in-reg softmax + XCD swizzle, verified)
//  + exp2-domain softmax: Qh pre-scaled by log2(e), so every exp is a raw
//    v_exp_f32 (no per-exp multiply; -20 VALU per kt).
//  + T13 defer-max: skip the alpha-rescale when __all(mx <= mrun + 11.54)
//    (P bounded by 2^11.54 ~ 2981, fits f16; sum ratio unchanged).
// ---------------------------------------------------------------------------
#define KST 72

__global__ __launch_bounds__(256) void attn_kernel(
    const f16* __restrict__ Qh, const f16* __restrict__ Kh,
    const f16* __restrict__ Vt, float* __restrict__ out)
{
    __shared__ f16 KS [64 * KST];
    __shared__ f16 VtS[64 * KST];
    __shared__ f16 PS [4][16 * KST];

    const int tid  = threadIdx.x;
    const int wave = tid >> 6;
    const int lane = tid & 63;
    const int ln   = lane & 15;
    const int quad = lane >> 4;

    // XCD swizzle: grid 4096 = 8 XCDs x 32 (b,p)-groups x 16 qt.
    const unsigned bid  = blockIdx.x;
    const unsigned xcd  = bid & 7;
    const unsigned slot = bid >> 3;            // 0..511
    const int qt = (int)(slot & 15u);
    const unsigned g = xcd * 32u + (slot >> 4);  // 0..255
    const int b = (int)(g >> 3);
    const int p = (int)(g & 7u);
    const size_t hb = (size_t)(b * HEADS + p) * NN * DD;

    // Q fragment: lane holds Q[q = qrow][k = ks*32 + quad*8 + j]  (B-frag, n=ln)
    const int qrow = qt * 64 + wave * 16 + ln;
    f16x8 qf[2];
    #pragma unroll
    for (int ks = 0; ks < 2; ++ks)
        qf[ks] = *(const f16x8*)(Qh + hb + (size_t)qrow * DD + ks * 32 + quad * 8);

    // o[dt][r] = O[q = ln][d = dt*16 + quad*4 + r]
    f32x4 o[4];
    #pragma unroll
    for (int dt = 0; dt < 4; ++dt) o[dt] = (f32x4){0.f, 0.f, 0.f, 0.f};
    float lrun = 0.f;
    float mrun = -__builtin_inff();
    const float THR = 11.5416f;   // 8 nats in log2 units

    const int sr = tid >> 2, sc = (tid & 3) * 16;

    // Prologue: tile 0 into staging registers.
    f16x8 kreg0, kreg1, vreg0, vreg1;
    {
        const size_t gk = hb + (size_t)sr * DD + sc;
        kreg0 = *(const f16x8*)(Kh + gk);
        kreg1 = *(const f16x8*)(Kh + gk + 8);
        const size_t gv = hb + (size_t)sr * NN + sc;
        vreg0 = *(const f16x8*)(Vt + gv);
        vreg1 = *(const f16x8*)(Vt + gv + 8);
    }

    f16* Pw = &PS[wave][0];

    for (int kt = 0; kt < 16; ++kt) {
        __syncthreads();   // B1: all waves done reading previous tile's LDS
        *(f16x8*)&KS [sr * KST + sc]     = kreg0;
        *(f16x8*)&KS [sr * KST + sc + 8] = kreg1;
        *(f16x8*)&VtS[sr * KST + sc]     = vreg0;
        *(f16x8*)&VtS[sr * KST + sc + 8] = vreg1;
        if (kt < 15) {   // T14: next-tile loads fly during this tile's compute
            const size_t gk = hb + (size_t)((kt + 1) * 64 + sr) * DD + sc;
            kreg0 = *(const f16x8*)(Kh + gk);
            kreg1 = *(const f16x8*)(Kh + gk + 8);
            const size_t gv = hb + (size_t)sr * NN + (kt + 1) * 64 + sc;
            vreg0 = *(const f16x8*)(Vt + gv);
            vreg1 = *(const f16x8*)(Vt + gv + 8);
        }
        __syncthreads();   // B2: tile kt visible in LDS

        // S^T tile: s[nt][r] = S[q = ln][key = nt*16 + quad*4 + r]  (log2 domain)
        f32x4 s[4];
        #pragma unroll
        for (int nt = 0; nt < 4; ++nt) s[nt] = (f32x4){0.f, 0.f, 0.f, 0.f};
        #pragma unroll
        for (int ks = 0; ks < 2; ++ks) {
            #pragma unroll
            for (int nt = 0; nt < 4; ++nt) {
                f16x8 bk = *(const f16x8*)&KS[(nt * 16 + ln) * KST + ks * 32 + quad * 8];
                s[nt] = __builtin_amdgcn_mfma_f32_16x16x32_f16(bk, qf[ks], s[nt], 0, 0, 0);
            }
        }

        // Row max for q=ln: 15 in-reg fmax + 2 cross-quad shuffles.
        float mx = s[0][0];
        #pragma unroll
        for (int nt = 0; nt < 4; ++nt)
            #pragma unroll
            for (int r = 0; r < 4; ++r) mx = fmaxf(mx, s[nt][r]);
        mx = fmaxf(mx, __shfl_xor(mx, 16));
        mx = fmaxf(mx, __shfl_xor(mx, 32));

        // T13 defer-max: only rescale when some row's max grew past THR.
        if (__any(mx > mrun + THR)) {
            const float mnew = fmaxf(mrun, mx);
            const float alpha = __builtin_amdgcn_exp2f(mrun - mnew);  // 0 first tile
            mrun = mnew;
            lrun *= alpha;
            #pragma unroll
            for (int dt = 0; dt < 4; ++dt) {
                o[dt][0] *= alpha; o[dt][1] *= alpha;
                o[dt][2] *= alpha; o[dt][3] *= alpha;
            }
        }

        // P = exp2(S-m): fp32 row-sum in regs, packed f16 pairs to wave-private LDS.
        float lsum = 0.f;
        #pragma unroll
        for (int nt = 0; nt < 4; ++nt) {
            const float p0 = __builtin_amdgcn_exp2f(s[nt][0] - mrun);
            const float p1 = __builtin_amdgcn_exp2f(s[nt][1] - mrun);
            const float p2 = __builtin_amdgcn_exp2f(s[nt][2] - mrun);
            const float p3 = __builtin_amdgcn_exp2f(s[nt][3] - mrun);
            lsum += (p0 + p1) + (p2 + p3);
            hf16x2 lo = __builtin_amdgcn_cvt_pkrtz(p0, p1);
            hf16x2 hi = __builtin_amdgcn_cvt_pkrtz(p2, p3);
            f16x4 pk = {(f16)lo.x, (f16)lo.y, (f16)hi.x, (f16)hi.y};
            *(f16x4*)&Pw[ln * KST + nt * 16 + quad * 4] = pk;   // ds_write_b64
        }
        lsum += __shfl_xor(lsum, 16);
        lsum += __shfl_xor(lsum, 32);
        lrun += lsum;

        // PS is wave-private: wave-local LDS drain instead of __syncthreads.
        asm volatile("s_waitcnt lgkmcnt(0)" ::: "memory");

        // O^T += V^T P :  o[dt] = mfma(A=V^T frag, B=P frag, o[dt])
        #pragma unroll
        for (int ks = 0; ks < 2; ++ks) {
            f16x8 pa = *(const f16x8*)&Pw[ln * KST + ks * 32 + quad * 8];
            #pragma unroll
            for (int dt = 0; dt < 4; ++dt) {
                f16x8 vb = *(const f16x8*)&VtS[(dt * 16 + ln) * KST + ks * 32 + quad * 8];
                o[dt] = __builtin_amdgcn_mfma_f32_16x16x32_f16(vb, pa, o[dt], 0, 0, 0);
            }
        }
    }

    // Epilogue: lane holds O[q=ln][d = dt*16+quad*4+r], l for q=ln.
    const float inv = 1.0f / lrun;
    const int nq = qt * 64 + wave * 16 + ln;
    #pragma unroll
    for (int dt = 0; dt < 4; ++dt) {
        const int c = p * DD + dt * 16 + quad * 4;
        #pragma unroll
        for (int r = 0; r < 4; ++r)
            out[((size_t)b * CC + c + r) * NN + nq] = o[dt][r] * inv;
    }
}

extern "C" void kernel_launch(void* const* d_in, const int* in_sizes, int n_in,
                              void* d_out, int out_size, void* d_ws, size_t ws_size,
                              hipStream_t stream) {
    const float* x     = (const float*)d_in[0];
    const float* qkv_w = (const float*)d_in[1];
    const float* h_pos = (const float*)d_in[2];
    const float* w_pos = (const float*)d_in[3];
    float* out = (float*)d_out;

    const size_t PT = (size_t)BB * HEADS * NN * DD;  // 16,777,216 elems
    f16* xt = (f16*)d_ws;
    f16* Qh = xt + PT;
    f16* Kh = Qh + PT;
    f16* Vt = Kh + PT;
    f16* Wh = Vt + PT;   // 3C*C = 786,432 f16; total ~135.7 MB (fits)

    wconv<<<dim3(3 * CC * CC / (256 * 8)), 256, 0, stream>>>(qkv_w, Wh);
    prep_x<<<dim3(CC / 64, NN / 64, BB), 256, 0, stream>>>(x, xt);
    qkv_mfma<<<dim3(3072), 256, 0, stream>>>(xt, Wh, h_pos, w_pos, Qh, Kh, Vt);
    attn_kernel<<<dim3(4096), 256, 0, stream>>>(Qh, Kh, Vt, out);
}